// Round 13
// baseline (766.539 us; speedup 1.0000x reference)
//
#include <hip/hip_runtime.h>
#include <math.h>

#define D 384
#define NCLS 20
#define FIN 80
#define CH 96

typedef unsigned int u32t;
typedef unsigned short u16t;
typedef __attribute__((ext_vector_type(8))) short bf16x8;
typedef __attribute__((ext_vector_type(4))) float f32x4;

__device__ __forceinline__ u16t f2bf(float f) {
    u32t b = __float_as_uint(f);
    u32t r = (b + 0x7FFFu + ((b >> 16) & 1u)) >> 16;
    return (u16t)r;
}
__device__ __forceinline__ float bfl(u32t u) { return __uint_as_float(u << 16); }
__device__ __forceinline__ float bfh(u32t u) { return __uint_as_float(u & 0xFFFF0000u); }

#define GLOAD16(g, l)                                                            \
    __builtin_amdgcn_global_load_lds(                                            \
        (const __attribute__((address_space(1))) void*)(g),                      \
        (__attribute__((address_space(3))) void*)(l), 16, 0, 0)

// ============================ CSR build ============================

__global__ void k_zero(int* p, int n) {
    int i = blockIdx.x * blockDim.x + threadIdx.x;
    if (i < n) p[i] = 0;
}

__global__ void k_hist(const int* __restrict__ dst, int* __restrict__ deg, int E) {
    int i = blockIdx.x * blockDim.x + threadIdx.x;
    if (i < E) atomicAdd(&deg[dst[i]], 1);
}

__global__ __launch_bounds__(256) void k_scan1(const int* __restrict__ deg,
                                               int* __restrict__ offs,
                                               int* __restrict__ bsum, int n) {
    __shared__ int sh[256];
    int t = threadIdx.x, i = blockIdx.x * 256 + t;
    int v = (i < n) ? deg[i] : 0;
    sh[t] = v;
    __syncthreads();
    for (int o = 1; o < 256; o <<= 1) {
        int a = (t >= o) ? sh[t - o] : 0;
        __syncthreads();
        sh[t] += a;
        __syncthreads();
    }
    if (i < n) offs[i] = sh[t] - v;
    if (t == 255) bsum[blockIdx.x] = sh[255];
}

__global__ __launch_bounds__(256) void k_scan2(int* __restrict__ bsum, int nb,
                                               int* __restrict__ offs, int n) {
    __shared__ int sh[256];
    int t = threadIdx.x;
    int v = (t < nb) ? bsum[t] : 0;
    sh[t] = v;
    __syncthreads();
    for (int o = 1; o < 256; o <<= 1) {
        int a = (t >= o) ? sh[t - o] : 0;
        __syncthreads();
        sh[t] += a;
        __syncthreads();
    }
    if (t < nb) bsum[t] = sh[t] - v;
    if (t == 255) offs[n] = sh[255];
}

__global__ __launch_bounds__(256) void k_scan3(int* __restrict__ offs,
                                               int* __restrict__ cursor,
                                               const int* __restrict__ bsum, int n) {
    int i = blockIdx.x * 256 + threadIdx.x;
    if (i < n) {
        int o = offs[i] + bsum[blockIdx.x];
        offs[i] = o;
        cursor[i] = o;
    }
}

// stores PRE-MULTIPLIED source row offset (src * 384 u32 = row in XSXD)
__global__ void k_scatter(const int* __restrict__ src, const int* __restrict__ dst,
                          int* __restrict__ cursor, int* __restrict__ csr_srcb, int E) {
    int i = blockIdx.x * blockDim.x + threadIdx.x;
    if (i < E) {
        int p = atomicAdd(&cursor[dst[i]], 1);
        csr_srcb[p] = src[i] * 384;
    }
}

// ============================ merged fp32 -> bf16 converter ============================
// seg0: x [N][80] -> xbf [N][128] (pad 0, Kp=128 for BK=64 GEMM)
// seg1/2: Wsrc0/Wdst0 [80][384] -> WT [384][128]T (pad 0)
// seg3..6: Wsrc1/Wdst1/Wsrc2/Wdst2 [384][384] -> WT [384][384]T
// seg7: Wc1 [384][96] -> Wc1T [128][384]T (pad 0)

__global__ __launch_bounds__(256) void k_cvt_all(
    const float* __restrict__ x,
    const float* __restrict__ Ws0, const float* __restrict__ Wd0,
    const float* __restrict__ Ws1, const float* __restrict__ Wd1,
    const float* __restrict__ Ws2, const float* __restrict__ Wd2,
    const float* __restrict__ Wc1,
    u16t* __restrict__ xbf,
    u16t* __restrict__ WT0s, u16t* __restrict__ WT0d,
    u16t* __restrict__ WT1s, u16t* __restrict__ WT1d,
    u16t* __restrict__ WT2s, u16t* __restrict__ WT2d,
    u16t* __restrict__ Wc1T, int N) {
    const int s128 = 384 * 128, s384 = 384 * 384, sc1 = 128 * 384;
    int i = blockIdx.x * 256 + threadIdx.x;

    int n0 = N * 128;
    if (i < n0) {
        int r = i >> 7, c = i & 127;
        xbf[i] = f2bf(c < FIN ? x[r * FIN + c] : 0.f);
        return;
    }
    i -= n0;
    if (i < 2 * s128) {
        const float* W = (i < s128) ? Ws0 : Wd0;
        u16t* O = (i < s128) ? WT0s : WT0d;
        int k2 = (i < s128) ? i : i - s128;
        int c = k2 >> 7, k = k2 & 127;
        O[k2] = f2bf(k < FIN ? W[(size_t)k * D + c] : 0.f);
        return;
    }
    i -= 2 * s128;
    if (i < 4 * s384) {
        int w = i / s384, k2 = i - w * s384;
        const float* W = (w == 0) ? Ws1 : (w == 1) ? Wd1 : (w == 2) ? Ws2 : Wd2;
        u16t* O = (w == 0) ? WT1s : (w == 1) ? WT1d : (w == 2) ? WT2s : WT2d;
        int c = k2 / 384, k = k2 - c * 384;
        O[k2] = f2bf(W[(size_t)k * D + c]);
        return;
    }
    i -= 4 * s384;
    if (i < sc1) {
        int c = i / D, k = i - c * D;
        Wc1T[i] = f2bf(c < CH ? Wc1[(size_t)k * CH + c] : 0.f);
    }
}

// ============================ bf16 MFMA GEMM, BK=64 ============================
// C[Mpad, ostride](bf16): C = A[Mpad,Kp] * BT[NB*128, Kp], Kp % 64 == 0.
// 128x128 tile, BK=64 (halved barrier count vs BK=32), 4 waves, 32 MFMA/iter.
// LDS [kc2(8)][row(128)][8]: chunk kc2 holds k-slice [kc2*8, kc2*8+8).
// Wave w stages chunks kc2 = {2w, 2w+1} x rows {0..63, 64..127} (4 A + 4 B).
// Grid transposed: blockIdx.x = column tile, blockIdx.y = M tile.

__global__ __launch_bounds__(256) void k_mm(const u16t* __restrict__ A,
                                            const u16t* __restrict__ BT,
                                            u16t* __restrict__ C, int Kp, int ostride) {
    __shared__ u16t Al[8][128][8];
    __shared__ u16t Bl[8][128][8];
    const int t = threadIdx.x;
    const int wave = t >> 6, lane = t & 63;
    const int wr = wave >> 1, wc = wave & 1;
    const int bm0 = blockIdx.y * 128;
    const int bn0 = blockIdx.x * 128;
    const int col16 = lane & 15, kc = lane >> 4;

    f32x4 acc[4][4] = {};

    // staging sources: chunk c -> i = c&1 (row half), kk = c>>1 (kc2 = wave*2+kk)
    const u16t* asrc[4];
    const u16t* bsrc[4];
    u16t* alds[4];
    u16t* blds[4];
#pragma unroll
    for (int c = 0; c < 4; c++) {
        int i = c & 1, kk = c >> 1;
        int kc2 = wave * 2 + kk;
        asrc[c] = A + (size_t)(bm0 + i * 64 + lane) * Kp + kc2 * 8;
        bsrc[c] = BT + (size_t)(bn0 + i * 64 + lane) * Kp + kc2 * 8;
        alds[c] = &Al[kc2][i * 64][0];
        blds[c] = &Bl[kc2][i * 64][0];
    }

    for (int k0 = 0; k0 < Kp; k0 += 64) {
#pragma unroll
        for (int c = 0; c < 4; c++) {
            GLOAD16(asrc[c] + k0, alds[c]);
            GLOAD16(bsrc[c] + k0, blds[c]);
        }
        __syncthreads();

#pragma unroll
        for (int kk2 = 0; kk2 < 2; kk2++) {
            bf16x8 a[4], b[4];
#pragma unroll
            for (int m = 0; m < 4; m++)
                a[m] = *(const bf16x8*)&Al[kc + kk2 * 4][wr * 64 + m * 16 + col16][0];
#pragma unroll
            for (int n = 0; n < 4; n++)
                b[n] = *(const bf16x8*)&Bl[kc + kk2 * 4][wc * 64 + n * 16 + col16][0];
#pragma unroll
            for (int m = 0; m < 4; m++)
#pragma unroll
                for (int n = 0; n < 4; n++)
                    acc[m][n] = __builtin_amdgcn_mfma_f32_16x16x32_bf16(
                        a[m], b[n], acc[m][n], 0, 0, 0);
        }
        __syncthreads();
    }

#pragma unroll
    for (int m = 0; m < 4; m++) {
#pragma unroll
        for (int n = 0; n < 4; n++) {
#pragma unroll
            for (int j = 0; j < 4; j++) {
                int row = bm0 + wr * 64 + m * 16 + (lane >> 4) * 4 + j;
                int col = bn0 + wc * 64 + n * 16 + col16;
                C[(size_t)row * ostride + col] = f2bf(acc[m][n][j]);
            }
        }
    }
}

// ============================ head GEMM: Yh[Mpad,96] = relu(Hbf @ Wc1 + bc1) ============================

__global__ __launch_bounds__(256) void k_mmh(const u16t* __restrict__ A,
                                             const u16t* __restrict__ BT,
                                             const float* __restrict__ bc1,
                                             float* __restrict__ Yh) {
    __shared__ u16t Al[4][128][8];
    __shared__ u16t Bl[4][128][8];
    const int t = threadIdx.x;
    const int wave = t >> 6, lane = t & 63;
    const int wr = wave >> 1, wc = wave & 1;
    const int bm0 = blockIdx.x * 128;
    const int col16 = lane & 15, kc = lane >> 4;

    f32x4 acc[4][4] = {};

    const u16t* asrc0 = A + (size_t)(bm0 + lane) * D + wave * 8;
    const u16t* asrc1 = A + (size_t)(bm0 + 64 + lane) * D + wave * 8;
    const u16t* bsrc0 = BT + (size_t)lane * D + wave * 8;
    const u16t* bsrc1 = BT + (size_t)(64 + lane) * D + wave * 8;
    u16t* alds0 = &Al[wave][0][0];
    u16t* alds1 = &Al[wave][64][0];
    u16t* blds0 = &Bl[wave][0][0];
    u16t* blds1 = &Bl[wave][64][0];

    for (int k0 = 0; k0 < D; k0 += 32) {
        GLOAD16(asrc0 + k0, alds0);
        GLOAD16(asrc1 + k0, alds1);
        GLOAD16(bsrc0 + k0, blds0);
        GLOAD16(bsrc1 + k0, blds1);
        __syncthreads();

        bf16x8 a[4], b[4];
#pragma unroll
        for (int m = 0; m < 4; m++)
            a[m] = *(const bf16x8*)&Al[kc][wr * 64 + m * 16 + col16][0];
#pragma unroll
        for (int n = 0; n < 4; n++)
            b[n] = *(const bf16x8*)&Bl[kc][wc * 64 + n * 16 + col16][0];
#pragma unroll
        for (int m = 0; m < 4; m++)
#pragma unroll
            for (int n = 0; n < 4; n++)
                acc[m][n] = __builtin_amdgcn_mfma_f32_16x16x32_bf16(
                    a[m], b[n], acc[m][n], 0, 0, 0);
        __syncthreads();
    }

#pragma unroll
    for (int m = 0; m < 4; m++) {
#pragma unroll
        for (int n = 0; n < 4; n++) {
            int col = wc * 64 + n * 16 + col16;
            if (col < CH) {
                float bc = bc1[col];
#pragma unroll
                for (int j = 0; j < 4; j++) {
                    int row = bm0 + wr * 64 + m * 16 + (lane >> 4) * 4 + j;
                    Yh[(size_t)row * CH + col] = fmaxf(acc[m][n][j] + bc, 0.f);
                }
            }
        }
    }
}

// ============================ fused GAT node kernel (round-11 version) ============================
// One wave per node; lane owns 6 channels. exp2-domain scores; bulk index
// load + readlane SGPR addressing; depth-1 row prefetch.

__global__ __launch_bounds__(256) void k_gat(const u32t* __restrict__ XSXD,
                                             const float* __restrict__ att,
                                             const float* __restrict__ bias,
                                             const float* __restrict__ gamma,
                                             const float* __restrict__ beta,
                                             const int* __restrict__ offs,
                                             const int* __restrict__ csr_srcb,
                                             u16t* __restrict__ Hout,
                                             int N) {
    int wave = threadIdx.x >> 6;
    int lane = threadIdx.x & 63;
    int node = blockIdx.x * 4 + wave;
    if (node >= N) return;
    int c0 = lane * 6;
    int lo3 = lane * 3;

    const u32t* xdp = XSXD + (size_t)node * 384 + 192 + lo3;
    u32t d0 = xdp[0], d1 = xdp[1], d2 = xdp[2];
    float xd[6] = {bfl(d0), bfh(d0), bfl(d1), bfh(d1), bfl(d2), bfh(d2)};
    float attr[6];
#pragma unroll
    for (int k = 0; k < 6; k++) attr[k] = att[c0 + k] * 1.44269504f;  // log2 e

    float m = -INFINITY, denom = 0.f;
    float acc[6] = {0.f, 0.f, 0.f, 0.f, 0.f, 0.f};
    int e0 = offs[node], e1 = offs[node + 1];

    for (int base = e0; base < e1; base += 64) {
        int cnt = min(64, e1 - base);
        u32t midx = (lane < cnt) ? (u32t)csr_srcb[base + lane] : 0u;
        u32t off = __builtin_amdgcn_readlane(midx, 0);
        const u32t* p = XSXD + off + lo3;
        u32t a0 = p[0], a1 = p[1], a2 = p[2];

        for (int j = 0; j < cnt; j++) {
            u32t b0 = a0, b1 = a1, b2 = a2;
            if (j + 1 < cnt) {
                u32t offn = __builtin_amdgcn_readlane(midx, j + 1);
                const u32t* pn = XSXD + offn + lo3;
                a0 = pn[0]; a1 = pn[1]; a2 = pn[2];
            }
            float xs[6] = {bfl(b0), bfh(b0), bfl(b1), bfh(b1), bfl(b2), bfh(b2)};
            float part = 0.f;
#pragma unroll
            for (int k = 0; k < 6; k++) {
                float v = xs[k] + xd[k];
                part = fmaf(fmaxf(v, 0.2f * v), attr[k], part);
            }
#pragma unroll
            for (int o = 1; o < 16; o <<= 1) part += __shfl_xor(part, o, 64);

            if (__builtin_expect(__any(part - m > 8.0f), 0)) {
                float nm = fmaxf(m, part);
                float r = __builtin_amdgcn_exp2f(m - nm);
                float pp = __builtin_amdgcn_exp2f(part - nm);
                denom = denom * r + pp;
#pragma unroll
                for (int k = 0; k < 6; k++) acc[k] = fmaf(pp, xs[k], acc[k] * r);
                m = nm;
            } else {
                float pp = __builtin_amdgcn_exp2f(part - m);
                denom += pp;
#pragma unroll
                for (int k = 0; k < 6; k++) acc[k] = fmaf(pp, xs[k], acc[k]);
            }
        }
    }

    float inv = 1.f / (denom + 1e-16f);
    float v[6];
    float s1 = 0.f;
#pragma unroll
    for (int k = 0; k < 6; k++) { v[k] = acc[k] * inv + bias[c0 + k]; s1 += v[k]; }
#pragma unroll
    for (int o = 1; o < 64; o <<= 1) s1 += __shfl_xor(s1, o, 64);
    float mu = s1 * (1.f / 384.f);
    float s2 = 0.f;
#pragma unroll
    for (int k = 0; k < 6; k++) { float d = v[k] - mu; s2 += d * d; }
#pragma unroll
    for (int o = 1; o < 64; o <<= 1) s2 += __shfl_xor(s2, o, 64);
    float rstd = rsqrtf(s2 * (1.f / 384.f) + 1e-5f);

    float ov[6];
#pragma unroll
    for (int k = 0; k < 6; k++) {
        float y = (v[k] - mu) * rstd * gamma[c0 + k] + beta[c0 + k];
        ov[k] = y > 0.f ? y : __expf(y) - 1.f;
    }
    u32t w0 = (u32t)f2bf(ov[0]) | ((u32t)f2bf(ov[1]) << 16);
    u32t w1 = (u32t)f2bf(ov[2]) | ((u32t)f2bf(ov[3]) << 16);
    u32t w2 = (u32t)f2bf(ov[4]) | ((u32t)f2bf(ov[5]) << 16);
    u32t* hp = (u32t*)Hout + (size_t)node * 192 + lo3;
    hp[0] = w0; hp[1] = w1; hp[2] = w2;
}

// ============================ LN + Wc2 output ============================

__global__ __launch_bounds__(256) void k_lnout(const float* __restrict__ Yh,
                                               const float* __restrict__ gc,
                                               const float* __restrict__ bec,
                                               const float* __restrict__ Wc2,
                                               const float* __restrict__ bc2,
                                               float* __restrict__ out, int N) {
    __shared__ float w2[CH * NCLS];
    __shared__ float ln[8][CH];
    int t = threadIdx.x;
    int g = t >> 5, tl = t & 31;
    int node = blockIdx.x * 8 + g;

    for (int i = t; i < CH * NCLS; i += 256) w2[i] = Wc2[i];

    if (node < N) {
        const float* yp = Yh + (size_t)node * CH;
        float y0 = yp[tl], y1 = yp[32 + tl], y2 = yp[64 + tl];
        float s = y0 + y1 + y2;
#pragma unroll
        for (int o = 1; o < 32; o <<= 1) s += __shfl_xor(s, o, 32);
        float mu = s * (1.f / CH);
        float d0 = y0 - mu, d1 = y1 - mu, d2 = y2 - mu;
        float q = d0 * d0 + d1 * d1 + d2 * d2;
#pragma unroll
        for (int o = 1; o < 32; o <<= 1) q += __shfl_xor(q, o, 32);
        float rstd = rsqrtf(q * (1.f / CH) + 1e-5f);
        ln[g][tl]      = d0 * rstd * gc[tl]      + bec[tl];
        ln[g][32 + tl] = d1 * rstd * gc[32 + tl] + bec[32 + tl];
        ln[g][64 + tl] = d2 * rstd * gc[64 + tl] + bec[64 + tl];
    }
    __syncthreads();

    if (node < N && tl < NCLS) {
        float o = bc2[tl];
        for (int c = 0; c < CH; c++) o += ln[g][c] * w2[c * NCLS + tl];
        out[(size_t)node * NCLS + tl] = o;
    }
}

// ============================ launch ============================

extern "C" void kernel_launch(void* const* d_in, const int* in_sizes, int n_in,
                              void* d_out, int out_size, void* d_ws, size_t ws_size,
                              hipStream_t stream) {
    const float* x        = (const float*)d_in[0];
    const int*   eidx     = (const int*)d_in[1];
    const float* Wsrc[3]  = {(const float*)d_in[2],  (const float*)d_in[8],  (const float*)d_in[14]};
    const float* Wdst[3]  = {(const float*)d_in[3],  (const float*)d_in[9],  (const float*)d_in[15]};
    const float* attw[3]  = {(const float*)d_in[4],  (const float*)d_in[10], (const float*)d_in[16]};
    const float* bia[3]   = {(const float*)d_in[5],  (const float*)d_in[11], (const float*)d_in[17]};
    const float* gam[3]   = {(const float*)d_in[6],  (const float*)d_in[12], (const float*)d_in[18]};
    const float* bet[3]   = {(const float*)d_in[7],  (const float*)d_in[13], (const float*)d_in[19]};
    const float* Wc1 = (const float*)d_in[20];
    const float* bc1 = (const float*)d_in[21];
    const float* gc  = (const float*)d_in[22];
    const float* bec = (const float*)d_in[23];
    const float* Wc2 = (const float*)d_in[24];
    const float* bc2 = (const float*)d_in[25];

    const int N = in_sizes[0] / FIN;
    const int E = in_sizes[1] / 2;
    const int Mpad = ((N + 127) / 128) * 128;
    const int* srcp = eidx;
    const int* dstp = eidx + E;

    // ---- workspace layout ----
    u16t* xbf  = (u16t*)d_ws;                         // Mpad*128 (Kp=128 padded)
    u16t* XSXD = xbf + (size_t)Mpad * 128;            // Mpad*768 (XS||XD per row)
    u16t* Hbf  = XSXD + (size_t)Mpad * 768;           // Mpad*384
    u16t* WT0s = Hbf + (size_t)Mpad * D;              // [384][128]
    u16t* WT0d = WT0s + 384 * 128;
    u16t* WT1s = WT0d + 384 * 128;                    // [384][384]
    u16t* WT1d = WT1s + 384 * 384;
    u16t* WT2s = WT1d + 384 * 384;
    u16t* WT2d = WT2s + 384 * 384;
    u16t* Wc1T = WT2d + 384 * 384;                    // [128][384]
    float* Yh  = (float*)(Wc1T + 128 * 384);          // Mpad*96 f32
    int* offs    = (int*)(Yh + (size_t)Mpad * CH);
    int* cursor  = offs + (N + 1);
    int* deg     = cursor + (N + 1);
    int* bsum    = deg + N;
    int* csr_srcb = bsum + 512;

    const int nb = (N + 255) / 256;

    // ---- CSR build ----
    k_zero<<<nb, 256, 0, stream>>>(deg, N);
    k_hist<<<(E + 255) / 256, 256, 0, stream>>>(dstp, deg, E);
    k_scan1<<<nb, 256, 0, stream>>>(deg, offs, bsum, N);
    k_scan2<<<1, 256, 0, stream>>>(bsum, nb, offs, N);
    k_scan3<<<nb, 256, 0, stream>>>(offs, cursor, bsum, N);
    k_scatter<<<(E + 255) / 256, 256, 0, stream>>>(srcp, dstp, cursor, csr_srcb, E);

    // ---- merged weight/input conversion ----
    {
        long total = (long)N * 128 + 2L * (384 * 128) + 4L * (384 * 384) + 128L * 384;
        int cblocks = (int)((total + 255) / 256);
        k_cvt_all<<<cblocks, 256, 0, stream>>>(
            x, Wsrc[0], Wdst[0], Wsrc[1], Wdst[1], Wsrc[2], Wdst[2], Wc1,
            xbf, WT0s, WT0d, WT1s, WT1d, WT2s, WT2d, Wc1T, N);
    }

    dim3 gmm(768 / 128, Mpad / 128);   // x = column tile, y = M tile
    int gatGrid = (N + 3) / 4;

    // ---- layer 0 (Kp = 128, zero-padded) ----
    k_mm<<<gmm, 256, 0, stream>>>(xbf, WT0s, XSXD, 128, 768);
    k_gat<<<gatGrid, 256, 0, stream>>>((const u32t*)XSXD, attw[0], bia[0], gam[0], bet[0],
                                       offs, csr_srcb, Hbf, N);
    // ---- layer 1 (Kp = 384) ----
    k_mm<<<gmm, 256, 0, stream>>>(Hbf, WT1s, XSXD, D, 768);
    k_gat<<<gatGrid, 256, 0, stream>>>((const u32t*)XSXD, attw[1], bia[1], gam[1], bet[1],
                                       offs, csr_srcb, Hbf, N);
    // ---- layer 2 (Kp = 384) ----
    k_mm<<<gmm, 256, 0, stream>>>(Hbf, WT2s, XSXD, D, 768);
    k_gat<<<gatGrid, 256, 0, stream>>>((const u32t*)XSXD, attw[2], bia[2], gam[2], bet[2],
                                       offs, csr_srcb, Hbf, N);

    // ---- classifier head: MFMA GEMM + LN/out ----
    k_mmh<<<Mpad / 128, 256, 0, stream>>>(Hbf, Wc1T, bc1, Yh);
    k_lnout<<<(N + 7) / 8, 256, 0, stream>>>(Yh, gc, bec, Wc2, bc2,
                                             (float*)d_out, N);
}

// Round 14
// 760.006 us; speedup vs baseline: 1.0086x; 1.0086x over previous
//
#include <hip/hip_runtime.h>
#include <math.h>

#define D 384
#define NCLS 20
#define FIN 80
#define CH 96

typedef unsigned int u32t;
typedef unsigned short u16t;
typedef __attribute__((ext_vector_type(8))) short bf16x8;
typedef __attribute__((ext_vector_type(4))) float f32x4;

__device__ __forceinline__ u16t f2bf(float f) {
    u32t b = __float_as_uint(f);
    u32t r = (b + 0x7FFFu + ((b >> 16) & 1u)) >> 16;
    return (u16t)r;
}
__device__ __forceinline__ float bfl(u32t u) { return __uint_as_float(u << 16); }
__device__ __forceinline__ float bfh(u32t u) { return __uint_as_float(u & 0xFFFF0000u); }

#define GLOAD16(g, l)                                                            \
    __builtin_amdgcn_global_load_lds(                                            \
        (const __attribute__((address_space(1))) void*)(g),                      \
        (__attribute__((address_space(3))) void*)(l), 16, 0, 0)

// ============================ CSR build ============================

__global__ void k_hist(const int* __restrict__ dst, int* __restrict__ deg, int E) {
    int i = blockIdx.x * blockDim.x + threadIdx.x;
    if (i < E) atomicAdd(&deg[dst[i]], 1);
}

__global__ __launch_bounds__(256) void k_scan1(const int* __restrict__ deg,
                                               int* __restrict__ offs,
                                               int* __restrict__ bsum, int n) {
    __shared__ int sh[256];
    int t = threadIdx.x, i = blockIdx.x * 256 + t;
    int v = (i < n) ? deg[i] : 0;
    sh[t] = v;
    __syncthreads();
    for (int o = 1; o < 256; o <<= 1) {
        int a = (t >= o) ? sh[t - o] : 0;
        __syncthreads();
        sh[t] += a;
        __syncthreads();
    }
    if (i < n) offs[i] = sh[t] - v;
    if (t == 255) bsum[blockIdx.x] = sh[255];
}

__global__ __launch_bounds__(256) void k_scan2(int* __restrict__ bsum, int nb,
                                               int* __restrict__ offs, int n) {
    __shared__ int sh[256];
    int t = threadIdx.x;
    int v = (t < nb) ? bsum[t] : 0;
    sh[t] = v;
    __syncthreads();
    for (int o = 1; o < 256; o <<= 1) {
        int a = (t >= o) ? sh[t - o] : 0;
        __syncthreads();
        sh[t] += a;
        __syncthreads();
    }
    if (t < nb) bsum[t] = sh[t] - v;
    if (t == 255) offs[n] = sh[255];
}

__global__ __launch_bounds__(256) void k_scan3(int* __restrict__ offs,
                                               int* __restrict__ cursor,
                                               const int* __restrict__ bsum, int n) {
    int i = blockIdx.x * 256 + threadIdx.x;
    if (i < n) {
        int o = offs[i] + bsum[blockIdx.x];
        offs[i] = o;
        cursor[i] = o;
    }
}

// stores PRE-MULTIPLIED source row offset (src * 384 u32 = row in XSXD)
__global__ void k_scatter(const int* __restrict__ src, const int* __restrict__ dst,
                          int* __restrict__ cursor, int* __restrict__ csr_srcb, int E) {
    int i = blockIdx.x * blockDim.x + threadIdx.x;
    if (i < E) {
        int p = atomicAdd(&cursor[dst[i]], 1);
        csr_srcb[p] = src[i] * 384;
    }
}

// ============================ merged fp32 -> bf16 converter ============================
// seg0: x [N][80] -> xbf [N][96] (pad 0)
// seg1/2: Wsrc0/Wdst0 [80][384] -> WT [384][96]T (pad 0)
// seg3..6: Wsrc1/Wdst1/Wsrc2/Wdst2 [384][384] -> WT [384][384]T
// seg7: Wc1 [384][96] -> Wc1T [128][384]T (pad 0)

__global__ __launch_bounds__(256) void k_cvt_all(
    const float* __restrict__ x,
    const float* __restrict__ Ws0, const float* __restrict__ Wd0,
    const float* __restrict__ Ws1, const float* __restrict__ Wd1,
    const float* __restrict__ Ws2, const float* __restrict__ Wd2,
    const float* __restrict__ Wc1,
    u16t* __restrict__ xbf,
    u16t* __restrict__ WT0s, u16t* __restrict__ WT0d,
    u16t* __restrict__ WT1s, u16t* __restrict__ WT1d,
    u16t* __restrict__ WT2s, u16t* __restrict__ WT2d,
    u16t* __restrict__ Wc1T, int N) {
    const int s96 = 384 * 96, s384 = 384 * 384, sc1 = 128 * 384;
    int i = blockIdx.x * 256 + threadIdx.x;

    int n0 = N * 96;
    if (i < n0) {
        int r = i / 96, c = i - r * 96;
        xbf[i] = f2bf(c < FIN ? x[r * FIN + c] : 0.f);
        return;
    }
    i -= n0;
    if (i < 2 * s96) {
        const float* W = (i < s96) ? Ws0 : Wd0;
        u16t* O = (i < s96) ? WT0s : WT0d;
        int k2 = (i < s96) ? i : i - s96;
        int c = k2 / 96, k = k2 - c * 96;
        O[k2] = f2bf(k < FIN ? W[(size_t)k * D + c] : 0.f);
        return;
    }
    i -= 2 * s96;
    if (i < 4 * s384) {
        int w = i / s384, k2 = i - w * s384;
        const float* W = (w == 0) ? Ws1 : (w == 1) ? Wd1 : (w == 2) ? Ws2 : Wd2;
        u16t* O = (w == 0) ? WT1s : (w == 1) ? WT1d : (w == 2) ? WT2s : WT2d;
        int c = k2 / 384, k = k2 - c * 384;
        O[k2] = f2bf(W[(size_t)k * D + c]);
        return;
    }
    i -= 4 * s384;
    if (i < sc1) {
        int c = i / D, k = i - c * D;
        Wc1T[i] = f2bf(c < CH ? Wc1[(size_t)k * CH + c] : 0.f);
    }
}

// ============================ bf16 MFMA GEMM (round-11 BK=32) ============================
// C[Mpad, ostride](bf16): C = A[Mpad,Kp] * BT[NB*128, Kp]
// 128x128 tile, BK=32, 4 waves (2x2 quadrants of 64x64), mfma 16x16x32 bf16.
// Grid transposed: blockIdx.x = column tile, blockIdx.y = M tile.

__global__ __launch_bounds__(256) void k_mm(const u16t* __restrict__ A,
                                            const u16t* __restrict__ BT,
                                            u16t* __restrict__ C, int Kp, int ostride) {
    __shared__ u16t Al[4][128][8];
    __shared__ u16t Bl[4][128][8];
    const int t = threadIdx.x;
    const int wave = t >> 6, lane = t & 63;
    const int wr = wave >> 1, wc = wave & 1;
    const int bm0 = blockIdx.y * 128;
    const int bn0 = blockIdx.x * 128;
    const int col16 = lane & 15, kc = lane >> 4;

    f32x4 acc[4][4] = {};

    const u16t* asrc0 = A + (size_t)(bm0 + lane) * Kp + wave * 8;
    const u16t* asrc1 = A + (size_t)(bm0 + 64 + lane) * Kp + wave * 8;
    const u16t* bsrc0 = BT + (size_t)(bn0 + lane) * Kp + wave * 8;
    const u16t* bsrc1 = BT + (size_t)(bn0 + 64 + lane) * Kp + wave * 8;
    u16t* alds0 = &Al[wave][0][0];
    u16t* alds1 = &Al[wave][64][0];
    u16t* blds0 = &Bl[wave][0][0];
    u16t* blds1 = &Bl[wave][64][0];

    for (int k0 = 0; k0 < Kp; k0 += 32) {
        GLOAD16(asrc0 + k0, alds0);
        GLOAD16(asrc1 + k0, alds1);
        GLOAD16(bsrc0 + k0, blds0);
        GLOAD16(bsrc1 + k0, blds1);
        __syncthreads();

        bf16x8 a[4], b[4];
#pragma unroll
        for (int m = 0; m < 4; m++)
            a[m] = *(const bf16x8*)&Al[kc][wr * 64 + m * 16 + col16][0];
#pragma unroll
        for (int n = 0; n < 4; n++)
            b[n] = *(const bf16x8*)&Bl[kc][wc * 64 + n * 16 + col16][0];
#pragma unroll
        for (int m = 0; m < 4; m++)
#pragma unroll
            for (int n = 0; n < 4; n++)
                acc[m][n] = __builtin_amdgcn_mfma_f32_16x16x32_bf16(
                    a[m], b[n], acc[m][n], 0, 0, 0);
        __syncthreads();
    }

#pragma unroll
    for (int m = 0; m < 4; m++) {
#pragma unroll
        for (int n = 0; n < 4; n++) {
#pragma unroll
            for (int j = 0; j < 4; j++) {
                int row = bm0 + wr * 64 + m * 16 + (lane >> 4) * 4 + j;
                int col = bn0 + wc * 64 + n * 16 + col16;
                C[(size_t)row * ostride + col] = f2bf(acc[m][n][j]);
            }
        }
    }
}

// ============================ fused head: relu(Hbf@Wc1+bc1) -> LN -> @Wc2+bc2 ============================
// One block per 128-row M-tile. MFMA GEMM (as k_mmh), relu result staged in
// LDS ys[128][100] (pad 100 breaks bank alignment), then LN per row (2
// threads/row, shfl combine) and the 96x20 output GEMM from LDS.

__global__ __launch_bounds__(256) void k_headf(const u16t* __restrict__ A,
                                               const u16t* __restrict__ BT,
                                               const float* __restrict__ bc1,
                                               const float* __restrict__ gc,
                                               const float* __restrict__ bec,
                                               const float* __restrict__ Wc2,
                                               const float* __restrict__ bc2,
                                               float* __restrict__ out, int N) {
    __shared__ u16t Al[4][128][8];
    __shared__ u16t Bl[4][128][8];
    __shared__ float ys[128][100];
    __shared__ float w2s[CH * NCLS];
    const int t = threadIdx.x;
    const int wave = t >> 6, lane = t & 63;
    const int wr = wave >> 1, wc = wave & 1;
    const int bm0 = blockIdx.x * 128;
    const int col16 = lane & 15, kc = lane >> 4;

    for (int i = t; i < CH * NCLS; i += 256) w2s[i] = Wc2[i];

    f32x4 acc[4][4] = {};

    const u16t* asrc0 = A + (size_t)(bm0 + lane) * D + wave * 8;
    const u16t* asrc1 = A + (size_t)(bm0 + 64 + lane) * D + wave * 8;
    const u16t* bsrc0 = BT + (size_t)lane * D + wave * 8;
    const u16t* bsrc1 = BT + (size_t)(64 + lane) * D + wave * 8;
    u16t* alds0 = &Al[wave][0][0];
    u16t* alds1 = &Al[wave][64][0];
    u16t* blds0 = &Bl[wave][0][0];
    u16t* blds1 = &Bl[wave][64][0];

    for (int k0 = 0; k0 < D; k0 += 32) {
        GLOAD16(asrc0 + k0, alds0);
        GLOAD16(asrc1 + k0, alds1);
        GLOAD16(bsrc0 + k0, blds0);
        GLOAD16(bsrc1 + k0, blds1);
        __syncthreads();

        bf16x8 a[4], b[4];
#pragma unroll
        for (int m = 0; m < 4; m++)
            a[m] = *(const bf16x8*)&Al[kc][wr * 64 + m * 16 + col16][0];
#pragma unroll
        for (int n = 0; n < 4; n++)
            b[n] = *(const bf16x8*)&Bl[kc][wc * 64 + n * 16 + col16][0];
#pragma unroll
        for (int m = 0; m < 4; m++)
#pragma unroll
            for (int n = 0; n < 4; n++)
                acc[m][n] = __builtin_amdgcn_mfma_f32_16x16x32_bf16(
                    a[m], b[n], acc[m][n], 0, 0, 0);
        __syncthreads();
    }

    // relu(acc + bc1) -> ys
#pragma unroll
    for (int m = 0; m < 4; m++) {
#pragma unroll
        for (int n = 0; n < 4; n++) {
            int col = wc * 64 + n * 16 + col16;
            if (col < CH) {
                float bc = bc1[col];
#pragma unroll
                for (int j = 0; j < 4; j++) {
                    int row = wr * 64 + m * 16 + (lane >> 4) * 4 + j;
                    ys[row][col] = fmaxf(acc[m][n][j] + bc, 0.f);
                }
            }
        }
    }
    __syncthreads();

    // LN + Wc2: 2 threads per row; thread (r, h) sums cols [h*48, h*48+48)
    int r = t >> 1, h = t & 1;
    int node = bm0 + r;
    float s = 0.f;
    for (int c = h * 48; c < h * 48 + 48; c++) s += ys[r][c];
    s += __shfl_xor(s, 1, 64);
    float mu = s * (1.f / CH);
    float q = 0.f;
    for (int c = h * 48; c < h * 48 + 48; c++) { float d = ys[r][c] - mu; q += d * d; }
    q += __shfl_xor(q, 1, 64);
    float rstd = rsqrtf(q * (1.f / CH) + 1e-5f);
    __syncthreads();   // all reads of raw ys done before overwrite
    for (int c = h * 48; c < h * 48 + 48; c++)
        ys[r][c] = (ys[r][c] - mu) * rstd * gc[c] + bec[c];
    __syncthreads();

    if (node < N) {
#pragma unroll
        for (int jj = 0; jj < NCLS / 2; jj++) {
            int j = h * (NCLS / 2) + jj;
            float o = bc2[j];
            for (int c = 0; c < CH; c++) o = fmaf(ys[r][c], w2s[c * NCLS + j], o);
            out[(size_t)node * NCLS + j] = o;
        }
    }
}

// ============================ fused GAT node kernel ============================
// 128-thread blocks (2 nodes/block) to reduce degree-variance stragglers.
// One wave per node; lane owns 6 channels. exp2-domain scores; bulk index
// load + readlane SGPR addressing; depth-1 row prefetch.

__global__ __launch_bounds__(128) void k_gat(const u32t* __restrict__ XSXD,
                                             const float* __restrict__ att,
                                             const float* __restrict__ bias,
                                             const float* __restrict__ gamma,
                                             const float* __restrict__ beta,
                                             const int* __restrict__ offs,
                                             const int* __restrict__ csr_srcb,
                                             u16t* __restrict__ Hout,
                                             int N) {
    int wave = threadIdx.x >> 6;
    int lane = threadIdx.x & 63;
    int node = blockIdx.x * 2 + wave;
    if (node >= N) return;
    int c0 = lane * 6;
    int lo3 = lane * 3;

    const u32t* xdp = XSXD + (size_t)node * 384 + 192 + lo3;
    u32t d0 = xdp[0], d1 = xdp[1], d2 = xdp[2];
    float xd[6] = {bfl(d0), bfh(d0), bfl(d1), bfh(d1), bfl(d2), bfh(d2)};
    float attr[6];
#pragma unroll
    for (int k = 0; k < 6; k++) attr[k] = att[c0 + k] * 1.44269504f;  // log2 e

    float m = -INFINITY, denom = 0.f;
    float acc[6] = {0.f, 0.f, 0.f, 0.f, 0.f, 0.f};
    int e0 = offs[node], e1 = offs[node + 1];

    for (int base = e0; base < e1; base += 64) {
        int cnt = min(64, e1 - base);
        u32t midx = (lane < cnt) ? (u32t)csr_srcb[base + lane] : 0u;
        u32t off = __builtin_amdgcn_readlane(midx, 0);
        const u32t* p = XSXD + off + lo3;
        u32t a0 = p[0], a1 = p[1], a2 = p[2];

        for (int j = 0; j < cnt; j++) {
            u32t b0 = a0, b1 = a1, b2 = a2;
            if (j + 1 < cnt) {
                u32t offn = __builtin_amdgcn_readlane(midx, j + 1);
                const u32t* pn = XSXD + offn + lo3;
                a0 = pn[0]; a1 = pn[1]; a2 = pn[2];
            }
            float xs[6] = {bfl(b0), bfh(b0), bfl(b1), bfh(b1), bfl(b2), bfh(b2)};
            float part = 0.f;
#pragma unroll
            for (int k = 0; k < 6; k++) {
                float v = xs[k] + xd[k];
                part = fmaf(fmaxf(v, 0.2f * v), attr[k], part);
            }
#pragma unroll
            for (int o = 1; o < 16; o <<= 1) part += __shfl_xor(part, o, 64);

            if (__builtin_expect(__any(part - m > 8.0f), 0)) {
                float nm = fmaxf(m, part);
                float r = __builtin_amdgcn_exp2f(m - nm);
                float pp = __builtin_amdgcn_exp2f(part - nm);
                denom = denom * r + pp;
#pragma unroll
                for (int k = 0; k < 6; k++) acc[k] = fmaf(pp, xs[k], acc[k] * r);
                m = nm;
            } else {
                float pp = __builtin_amdgcn_exp2f(part - m);
                denom += pp;
#pragma unroll
                for (int k = 0; k < 6; k++) acc[k] = fmaf(pp, xs[k], acc[k]);
            }
        }
    }

    float inv = 1.f / (denom + 1e-16f);
    float v[6];
    float s1 = 0.f;
#pragma unroll
    for (int k = 0; k < 6; k++) { v[k] = acc[k] * inv + bias[c0 + k]; s1 += v[k]; }
#pragma unroll
    for (int o = 1; o < 64; o <<= 1) s1 += __shfl_xor(s1, o, 64);
    float mu = s1 * (1.f / 384.f);
    float s2 = 0.f;
#pragma unroll
    for (int k = 0; k < 6; k++) { float d = v[k] - mu; s2 += d * d; }
#pragma unroll
    for (int o = 1; o < 64; o <<= 1) s2 += __shfl_xor(s2, o, 64);
    float rstd = rsqrtf(s2 * (1.f / 384.f) + 1e-5f);

    float ov[6];
#pragma unroll
    for (int k = 0; k < 6; k++) {
        float y = (v[k] - mu) * rstd * gamma[c0 + k] + beta[c0 + k];
        ov[k] = y > 0.f ? y : __expf(y) - 1.f;
    }
    u32t w0 = (u32t)f2bf(ov[0]) | ((u32t)f2bf(ov[1]) << 16);
    u32t w1 = (u32t)f2bf(ov[2]) | ((u32t)f2bf(ov[3]) << 16);
    u32t w2 = (u32t)f2bf(ov[4]) | ((u32t)f2bf(ov[5]) << 16);
    u32t* hp = (u32t*)Hout + (size_t)node * 192 + lo3;
    hp[0] = w0; hp[1] = w1; hp[2] = w2;
}

// ============================ launch ============================

extern "C" void kernel_launch(void* const* d_in, const int* in_sizes, int n_in,
                              void* d_out, int out_size, void* d_ws, size_t ws_size,
                              hipStream_t stream) {
    const float* x        = (const float*)d_in[0];
    const int*   eidx     = (const int*)d_in[1];
    const float* Wsrc[3]  = {(const float*)d_in[2],  (const float*)d_in[8],  (const float*)d_in[14]};
    const float* Wdst[3]  = {(const float*)d_in[3],  (const float*)d_in[9],  (const float*)d_in[15]};
    const float* attw[3]  = {(const float*)d_in[4],  (const float*)d_in[10], (const float*)d_in[16]};
    const float* bia[3]   = {(const float*)d_in[5],  (const float*)d_in[11], (const float*)d_in[17]};
    const float* gam[3]   = {(const float*)d_in[6],  (const float*)d_in[12], (const float*)d_in[18]};
    const float* bet[3]   = {(const float*)d_in[7],  (const float*)d_in[13], (const float*)d_in[19]};
    const float* Wc1 = (const float*)d_in[20];
    const float* bc1 = (const float*)d_in[21];
    const float* gc  = (const float*)d_in[22];
    const float* bec = (const float*)d_in[23];
    const float* Wc2 = (const float*)d_in[24];
    const float* bc2 = (const float*)d_in[25];

    const int N = in_sizes[0] / FIN;
    const int E = in_sizes[1] / 2;
    const int Mpad = ((N + 127) / 128) * 128;
    const int* srcp = eidx;
    const int* dstp = eidx + E;

    // ---- workspace layout ----
    u16t* xbf  = (u16t*)d_ws;                         // Mpad*96
    u16t* XSXD = xbf + (size_t)Mpad * 96;             // Mpad*768 (XS||XD per row)
    u16t* Hbf  = XSXD + (size_t)Mpad * 768;           // Mpad*384
    u16t* WT0s = Hbf + (size_t)Mpad * D;              // [384][96]
    u16t* WT0d = WT0s + 384 * 96;
    u16t* WT1s = WT0d + 384 * 96;                     // [384][384]
    u16t* WT1d = WT1s + 384 * 384;
    u16t* WT2s = WT1d + 384 * 384;
    u16t* WT2d = WT2s + 384 * 384;
    u16t* Wc1T = WT2d + 384 * 384;                    // [128][384]
    int* offs    = (int*)(Wc1T + 128 * 384);
    int* cursor  = offs + (N + 1);
    int* deg     = cursor + (N + 1);
    int* bsum    = deg + N;
    int* csr_srcb = bsum + 512;

    const int nb = (N + 255) / 256;

    // ---- CSR build ----
    hipMemsetAsync(deg, 0, (size_t)N * sizeof(int), stream);
    k_hist<<<(E + 255) / 256, 256, 0, stream>>>(dstp, deg, E);
    k_scan1<<<nb, 256, 0, stream>>>(deg, offs, bsum, N);
    k_scan2<<<1, 256, 0, stream>>>(bsum, nb, offs, N);
    k_scan3<<<nb, 256, 0, stream>>>(offs, cursor, bsum, N);
    k_scatter<<<(E + 255) / 256, 256, 0, stream>>>(srcp, dstp, cursor, csr_srcb, E);

    // ---- merged weight/input conversion ----
    {
        long total = (long)N * 96 + 2L * (384 * 96) + 4L * (384 * 384) + 128L * 384;
        int cblocks = (int)((total + 255) / 256);
        k_cvt_all<<<cblocks, 256, 0, stream>>>(
            x, Wsrc[0], Wdst[0], Wsrc[1], Wdst[1], Wsrc[2], Wdst[2], Wc1,
            xbf, WT0s, WT0d, WT1s, WT1d, WT2s, WT2d, Wc1T, N);
    }

    dim3 gmm(768 / 128, Mpad / 128);   // x = column tile, y = M tile
    int gatGrid = (N + 1) / 2;

    // ---- layer 0 (Kp = 96) ----
    k_mm<<<gmm, 256, 0, stream>>>(xbf, WT0s, XSXD, 96, 768);
    k_gat<<<gatGrid, 128, 0, stream>>>((const u32t*)XSXD, attw[0], bia[0], gam[0], bet[0],
                                       offs, csr_srcb, Hbf, N);
    // ---- layer 1 (Kp = 384) ----
    k_mm<<<gmm, 256, 0, stream>>>(Hbf, WT1s, XSXD, D, 768);
    k_gat<<<gatGrid, 128, 0, stream>>>((const u32t*)XSXD, attw[1], bia[1], gam[1], bet[1],
                                       offs, csr_srcb, Hbf, N);
    // ---- layer 2 (Kp = 384) ----
    k_mm<<<gmm, 256, 0, stream>>>(Hbf, WT2s, XSXD, D, 768);
    k_gat<<<gatGrid, 128, 0, stream>>>((const u32t*)XSXD, attw[2], bia[2], gam[2], bet[2],
                                       offs, csr_srcb, Hbf, N);

    // ---- fused classifier head ----
    k_headf<<<Mpad / 128, 256, 0, stream>>>(Hbf, Wc1T, bc1, gc, bec, Wc2, bc2,
                                            (float*)d_out, N);
}